// Round 5
// baseline (417.885 us; speedup 1.0000x reference)
//
#include <hip/hip_runtime.h>
#include <hip/hip_bf16.h>

// Joiner: out[b,t,u,v] = (enc[b,t,:]+pred[b,u,:])·W[v,:] + bias[v]
// Decomposition: E = enc·W^T, P = pred·W^T; out = E + P + bias.
// B=8, T=200, U=50, D=512, V=1024.
//
// MEASUREMENT ROUND (resubmit; R4 hit an infra failure, not a kernel failure):
// bcast_kernel is launched TWICE (idempotent: reads workspace EP, writes
// identical values to out). dur_us(this) - dur_us(R3=357.8) = standalone bcast
// duration. This splits the unattributed ~300 us between {harness fill in
// timed window, gemm, bcast}. No other byte changed vs R3.

typedef __attribute__((ext_vector_type(8))) short bf16x8;   // 8 bf16 in 4 VGPRs
typedef __attribute__((ext_vector_type(4))) float f32x4;

__device__ __forceinline__ unsigned short f2bf(float f) {
    union { float f; unsigned int u; } x; x.f = f;
    unsigned int u = x.u;
    unsigned int r = (u + 0x7fffu + ((u >> 16) & 1u)) >> 16;  // RNE
    return (unsigned short)r;
}

// ---- kernel 1: convert enc(819200) ‖ pred(204800) ‖ W(524288) fp32 -> bf16 ----
__global__ __launch_bounds__(256) void cvt_kernel(const float* __restrict__ enc,
                                                  const float* __restrict__ pred,
                                                  const float* __restrict__ W,
                                                  unsigned short* __restrict__ dst) {
    int i4 = (blockIdx.x * 256 + threadIdx.x) * 4;   // 1512*256*4 = 1,548,288 exact
    const float* src;
    if (i4 < 819200)        src = enc  + i4;
    else if (i4 < 1024000)  src = pred + (i4 - 819200);
    else                    src = W    + (i4 - 1024000);
    float4 f = *(const float4*)src;
    ushort4 o;
    o.x = f2bf(f.x); o.y = f2bf(f.y); o.z = f2bf(f.z); o.w = f2bf(f.w);
    *(ushort4*)(dst + i4) = o;
}

// ---- kernel 2: EP[2000][1024] = A[2000][512] · W^T  (bf16 MFMA, fp32 acc) ----
// 16x64 strip per wave (unchanged from R3).
__global__ __launch_bounds__(256) void gemm_kernel(const unsigned short* __restrict__ A,
                                                   const unsigned short* __restrict__ Wb,
                                                   float* __restrict__ EP) {
    int lane = threadIdx.x & 63;
    int wave = threadIdx.x >> 6;
    int quad = lane >> 4;
    int l16  = lane & 15;
    int mw = blockIdx.x * 64 + wave * 16;   // grid.x=32 -> 2048 rows
    int n0 = blockIdx.y * 64;               // grid.y=16 -> 1024 cols
    int row = mw + l16; if (row > 1999) row = 1999;   // clamp loads; stores guarded
    const bf16x8* ap = (const bf16x8*)(A  + row * 512 + quad * 8);
    const bf16x8* b0 = (const bf16x8*)(Wb + (n0      + l16) * 512 + quad * 8);
    const bf16x8* b1 = (const bf16x8*)(Wb + (n0 + 16 + l16) * 512 + quad * 8);
    const bf16x8* b2 = (const bf16x8*)(Wb + (n0 + 32 + l16) * 512 + quad * 8);
    const bf16x8* b3 = (const bf16x8*)(Wb + (n0 + 48 + l16) * 512 + quad * 8);
    f32x4 acc0 = {0.f,0.f,0.f,0.f}, acc1 = {0.f,0.f,0.f,0.f};
    f32x4 acc2 = {0.f,0.f,0.f,0.f}, acc3 = {0.f,0.f,0.f,0.f};
#pragma unroll
    for (int kk = 0; kk < 16; ++kk) {  // K = 512 = 16 * 32
        bf16x8 a = ap[kk * 4];
        acc0 = __builtin_amdgcn_mfma_f32_16x16x32_bf16(a, b0[kk * 4], acc0, 0, 0, 0);
        acc1 = __builtin_amdgcn_mfma_f32_16x16x32_bf16(a, b1[kk * 4], acc1, 0, 0, 0);
        acc2 = __builtin_amdgcn_mfma_f32_16x16x32_bf16(a, b2[kk * 4], acc2, 0, 0, 0);
        acc3 = __builtin_amdgcn_mfma_f32_16x16x32_bf16(a, b3[kk * 4], acc3, 0, 0, 0);
    }
    // C/D layout (m89-verified): col = n + l16, row = mw + quad*4 + i
#pragma unroll
    for (int i = 0; i < 4; ++i) {
        int r = mw + quad * 4 + i;
        if (r < 2000) {
            float* er = EP + r * 1024 + l16;
            er[n0     ] = acc0[i];
            er[n0 + 16] = acc1[i];
            er[n0 + 32] = acc2[i];
            er[n0 + 48] = acc3[i];
        }
    }
}

// ---- kernel 3: out[bt][u][v] = E[bt][v] + P[b*50+u][v] + bias[v] ----
// UNCHANGED from R1/R3. Launched twice this round as a timing probe.
__global__ __launch_bounds__(512) void bcast_kernel(const float* __restrict__ EP,
                                                    const float* __restrict__ bias,
                                                    float* __restrict__ out) {
    int bt   = blockIdx.x;            // 0..1599 ; b = bt / 200
    int b    = bt / 200;
    int half = threadIdx.x >> 8;      // 0: even u, 1: odd u
    int v0   = (threadIdx.x & 255) * 4;

    f32x4 e = *(const f32x4*)(EP + bt * 1024 + v0);
    e += *(const f32x4*)(bias + v0);

    const float* Pb = EP + (size_t)(1600 + b * 50 + half) * 1024 + v0;
    float*       ob = out + (size_t)bt * 51200 + (size_t)half * 1024 + v0;

    f32x4 p = *(const f32x4*)Pb;
#pragma unroll
    for (int i = 0; i < 24; ++i) {            // u = 2i + half
        f32x4 pn = *(const f32x4*)(Pb + (i + 1) * 2048);   // prefetch next
        *(f32x4*)(ob + i * 2048) = e + p;
        p = pn;
    }
    *(f32x4*)(ob + 24 * 2048) = e + p;
}

// ---- fallback (only if ws too small): direct fp32 compute ----
__global__ __launch_bounds__(256) void fallback_kernel(const float* __restrict__ enc,
                                                       const float* __restrict__ pred,
                                                       const float* __restrict__ W,
                                                       const float* __restrict__ bias,
                                                       float* __restrict__ out) {
    int btu = blockIdx.x;           // 0..79999
    int u  = btu % 50;
    int bt = btu / 50;
    int b  = bt / 200;
    __shared__ float j[512];
    const float* e = enc  + bt * 512;
    const float* p = pred + (b * 50 + u) * 512;
    for (int k = threadIdx.x; k < 512; k += 256) j[k] = e[k] + p[k];
    __syncthreads();
    int v = threadIdx.x * 4;
    float a0 = bias[v], a1 = bias[v + 1], a2 = bias[v + 2], a3 = bias[v + 3];
    for (int k = 0; k < 512; k += 4) {
        float4 jk = *(const float4*)(j + k);
        float4 w0 = *(const float4*)(W + (v + 0) * 512 + k);
        float4 w1 = *(const float4*)(W + (v + 1) * 512 + k);
        float4 w2 = *(const float4*)(W + (v + 2) * 512 + k);
        float4 w3 = *(const float4*)(W + (v + 3) * 512 + k);
        a0 += jk.x * w0.x + jk.y * w0.y + jk.z * w0.z + jk.w * w0.w;
        a1 += jk.x * w1.x + jk.y * w1.y + jk.z * w1.z + jk.w * w1.w;
        a2 += jk.x * w2.x + jk.y * w2.y + jk.z * w2.z + jk.w * w2.w;
        a3 += jk.x * w3.x + jk.y * w3.y + jk.z * w3.z + jk.w * w3.w;
    }
    size_t o = (size_t)btu * 1024 + v;
    out[o] = a0; out[o + 1] = a1; out[o + 2] = a2; out[o + 3] = a3;
}

extern "C" void kernel_launch(void* const* d_in, const int* in_sizes, int n_in,
                              void* d_out, int out_size, void* d_ws, size_t ws_size,
                              hipStream_t stream) {
    const float* enc  = (const float*)d_in[0];
    const float* pred = (const float*)d_in[1];
    const float* W    = (const float*)d_in[2];
    const float* bias = (const float*)d_in[3];
    float* out = (float*)d_out;

    // ws layout: A_bf16 [2000*512] (2,048,000 B) | W_bf16 [1024*512] (1,048,576 B) | EP fp32 [2000*1024] (8,192,000 B)
    const size_t NEED = 2048000u + 1048576u + 8192000u;
    if (ws_size >= NEED) {
        unsigned short* AB = (unsigned short*)d_ws;
        float* EP = (float*)((char*)d_ws + 2048000 + 1048576);
        cvt_kernel<<<1512, 256, 0, stream>>>(enc, pred, W, AB);
        gemm_kernel<<<dim3(32, 16), 256, 0, stream>>>(AB, AB + 1024000, EP);
        bcast_kernel<<<1600, 512, 0, stream>>>(EP, bias, out);
        // PROBE: second identical (idempotent) launch — this-round dur minus
        // R3's 357.8 us isolates bcast's standalone duration.
        bcast_kernel<<<1600, 512, 0, stream>>>(EP, bias, out);
    } else {
        fallback_kernel<<<80000, 256, 0, stream>>>(enc, pred, W, bias, out);
    }
}

// Round 6
// 367.573 us; speedup vs baseline: 1.1369x; 1.1369x over previous
//
#include <hip/hip_runtime.h>
#include <hip/hip_bf16.h>

// Joiner: out[b,t,u,v] = (enc[b,t,:]+pred[b,u,:])·W[v,:] + bias[v]
// Decomposition: P = pred·W^T (tiny standalone GEMM); E = enc·W^T computed
// INSIDE the broadcast kernel (fused), so the E-GEMM hides under the
// mandatory 327.68 MB output-store stream.
// B=8, T=200, U=50, D=512, V=1024.
//
// R5 probe result: bcast=60us (~floor), fill~212us fixed in-window, cvt~3us,
// gemm~83us (17x its L2-BW floor, cause unknown). Fusion removes the 83us
// from the critical path instead of diagnosing it.

typedef __attribute__((ext_vector_type(8))) short bf16x8;   // 8 bf16 in 4 VGPRs
typedef __attribute__((ext_vector_type(4))) float f32x4;

__device__ __forceinline__ unsigned short f2bf(float f) {
    union { float f; unsigned int u; } x; x.f = f;
    unsigned int u = x.u;
    unsigned int r = (u + 0x7fffu + ((u >> 16) & 1u)) >> 16;  // RNE
    return (unsigned short)r;
}

// ---- kernel 1: convert enc(819200) ‖ pred(204800) ‖ W(524288) fp32 -> bf16 ----
__global__ __launch_bounds__(256) void cvt_kernel(const float* __restrict__ enc,
                                                  const float* __restrict__ pred,
                                                  const float* __restrict__ W,
                                                  unsigned short* __restrict__ dst) {
    int i4 = (blockIdx.x * 256 + threadIdx.x) * 4;   // 1512*256*4 = 1,548,288 exact
    const float* src;
    if (i4 < 819200)        src = enc  + i4;
    else if (i4 < 1024000)  src = pred + (i4 - 819200);
    else                    src = W    + (i4 - 1024000);
    float4 f = *(const float4*)src;
    ushort4 o;
    o.x = f2bf(f.x); o.y = f2bf(f.y); o.z = f2bf(f.z); o.w = f2bf(f.w);
    *(ushort4*)(dst + i4) = o;
}

// ---- kernel 2: EP rows [row_base..row_base+grid.x*64) = A-rows · W^T ----
// R3's proven 16x64-per-wave GEMM, now parameterized by row_base; used ONLY
// for the P part (rows 1600..1999, 0.42 GFLOP).
__global__ __launch_bounds__(256) void gemm_kernel(const unsigned short* __restrict__ A,
                                                   const unsigned short* __restrict__ Wb,
                                                   float* __restrict__ EP,
                                                   int row_base) {
    int lane = threadIdx.x & 63;
    int wave = threadIdx.x >> 6;
    int quad = lane >> 4;
    int l16  = lane & 15;
    int mw = row_base + blockIdx.x * 64 + wave * 16;
    int n0 = blockIdx.y * 64;
    int row = mw + l16; if (row > 1999) row = 1999;   // clamp loads; stores guarded
    const bf16x8* ap = (const bf16x8*)(A  + row * 512 + quad * 8);
    const bf16x8* b0 = (const bf16x8*)(Wb + (n0      + l16) * 512 + quad * 8);
    const bf16x8* b1 = (const bf16x8*)(Wb + (n0 + 16 + l16) * 512 + quad * 8);
    const bf16x8* b2 = (const bf16x8*)(Wb + (n0 + 32 + l16) * 512 + quad * 8);
    const bf16x8* b3 = (const bf16x8*)(Wb + (n0 + 48 + l16) * 512 + quad * 8);
    f32x4 acc0 = {0.f,0.f,0.f,0.f}, acc1 = {0.f,0.f,0.f,0.f};
    f32x4 acc2 = {0.f,0.f,0.f,0.f}, acc3 = {0.f,0.f,0.f,0.f};
#pragma unroll
    for (int kk = 0; kk < 16; ++kk) {  // K = 512 = 16 * 32
        bf16x8 a = ap[kk * 4];
        acc0 = __builtin_amdgcn_mfma_f32_16x16x32_bf16(a, b0[kk * 4], acc0, 0, 0, 0);
        acc1 = __builtin_amdgcn_mfma_f32_16x16x32_bf16(a, b1[kk * 4], acc1, 0, 0, 0);
        acc2 = __builtin_amdgcn_mfma_f32_16x16x32_bf16(a, b2[kk * 4], acc2, 0, 0, 0);
        acc3 = __builtin_amdgcn_mfma_f32_16x16x32_bf16(a, b3[kk * 4], acc3, 0, 0, 0);
    }
    // C/D layout (m89-verified): col = n + l16, row = mw + quad*4 + i
#pragma unroll
    for (int i = 0; i < 4; ++i) {
        int r = mw + quad * 4 + i;
        if (r < 2000) {
            float* er = EP + r * 1024 + l16;
            er[n0     ] = acc0[i];
            er[n0 + 16] = acc1[i];
            er[n0 + 32] = acc2[i];
            er[n0 + 48] = acc3[i];
        }
    }
}

// ---- kernel 3 (FUSED): per block = 16 bt-rows x 128 v-cols ----
// Step 1: E-tile[16][128] = enc_bf16[bt0..bt0+15] · W^T[:,v0..v0+127] via the
//         R3 MFMA loop (each of 4 waves owns 32 cols = 2 fragments).
// Step 2: E-tile -> LDS (R3's epilogue index map, local coords).
// Step 3: stream out[bt][u][v] = E + P[b*50+u][v] + bias[v] for u=0..49.
// Grid (100, 8) = 800 blocks (~3.1/CU) so K-loops of resident blocks overlap
// the store streams of their neighbors.
__global__ __launch_bounds__(256) void fused_kernel(const unsigned short* __restrict__ AB,
                                                    const unsigned short* __restrict__ Wb,
                                                    const float* __restrict__ EP,
                                                    const float* __restrict__ bias,
                                                    float* __restrict__ out) {
    __shared__ f32x4 e_lds4[16][32];                 // [16 rows][128 cols] fp32, 16B-aligned
    int lane = threadIdx.x & 63;
    int wave = threadIdx.x >> 6;
    int quad = lane >> 4;
    int l16  = lane & 15;
    int bt0 = blockIdx.x * 16;                       // 0..1584 (no row OOB: 1584+15=1599)
    int v0  = blockIdx.y * 128;                      // 0..896

    // ---- step 1: MFMA K-loop (identical structure to R3's proven gemm) ----
    int nb = v0 + wave * 32;
    const bf16x8* ap  = (const bf16x8*)(AB + (bt0 + l16) * 512 + quad * 8);
    const bf16x8* bp0 = (const bf16x8*)(Wb + (nb      + l16) * 512 + quad * 8);
    const bf16x8* bp1 = (const bf16x8*)(Wb + (nb + 16 + l16) * 512 + quad * 8);
    f32x4 acc0 = {0.f,0.f,0.f,0.f}, acc1 = {0.f,0.f,0.f,0.f};
#pragma unroll
    for (int kk = 0; kk < 16; ++kk) {                // K = 512 = 16 * 32
        bf16x8 a = ap[kk * 4];
        acc0 = __builtin_amdgcn_mfma_f32_16x16x32_bf16(a, bp0[kk * 4], acc0, 0, 0, 0);
        acc1 = __builtin_amdgcn_mfma_f32_16x16x32_bf16(a, bp1[kk * 4], acc1, 0, 0, 0);
    }

    // ---- step 2: E-tile to LDS (row = quad*4+i, col = wave*32 + f*16 + l16) ----
    float* ef = (float*)&e_lds4[0][0];
    int cl0 = wave * 32 + l16;
#pragma unroll
    for (int i = 0; i < 4; ++i) {
        int rl = quad * 4 + i;
        ef[rl * 128 + cl0     ] = acc0[i];
        ef[rl * 128 + cl0 + 16] = acc1[i];
    }
    __syncthreads();

    // ---- step 3: broadcast stream ----
    // lanes 0-31 handle row r0 = wave*4 + 0/1 (+half), lanes 32-63 the paired row;
    // each (u, jj) store instr writes two contiguous 512B segments.
    int half = lane >> 5;
    int l32  = lane & 31;
    f32x4 bv = *(const f32x4*)(bias + v0 + l32 * 4);
    int r0 = wave * 4 + half;        // rows {0,1,4,5,8,9,12,13} across waves
    int r1 = r0 + 2;                 // rows {2,3,6,7,10,11,14,15}
    f32x4 e0 = e_lds4[r0][l32] + bv;
    f32x4 e1 = e_lds4[r1][l32] + bv;
    int btA = bt0 + r0, btB = bt0 + r1;
    // P rows live at EP rows 1600 + b*50 + u ; b can differ between r0 and r1
    const float* P0 = EP + (size_t)(1600 + (btA / 200) * 50) * 1024 + v0 + l32 * 4;
    const float* P1 = EP + (size_t)(1600 + (btB / 200) * 50) * 1024 + v0 + l32 * 4;
    float* o0 = out + (size_t)btA * 51200 + v0 + l32 * 4;
    float* o1 = out + (size_t)btB * 51200 + v0 + l32 * 4;
#pragma unroll 5
    for (int u = 0; u < 50; ++u) {
        f32x4 p0 = *(const f32x4*)(P0 + u * 1024);
        f32x4 p1 = *(const f32x4*)(P1 + u * 1024);
        *(f32x4*)(o0 + u * 1024) = e0 + p0;
        *(f32x4*)(o1 + u * 1024) = e1 + p1;
    }
}

// ---- fallback (only if ws too small): direct fp32 compute ----
__global__ __launch_bounds__(256) void fallback_kernel(const float* __restrict__ enc,
                                                       const float* __restrict__ pred,
                                                       const float* __restrict__ W,
                                                       const float* __restrict__ bias,
                                                       float* __restrict__ out) {
    int btu = blockIdx.x;           // 0..79999
    int u  = btu % 50;
    int bt = btu / 50;
    int b  = bt / 200;
    __shared__ float j[512];
    const float* e = enc  + bt * 512;
    const float* p = pred + (b * 50 + u) * 512;
    for (int k = threadIdx.x; k < 512; k += 256) j[k] = e[k] + p[k];
    __syncthreads();
    int v = threadIdx.x * 4;
    float a0 = bias[v], a1 = bias[v + 1], a2 = bias[v + 2], a3 = bias[v + 3];
    for (int k = 0; k < 512; k += 4) {
        float4 jk = *(const float4*)(j + k);
        float4 w0 = *(const float4*)(W + (v + 0) * 512 + k);
        float4 w1 = *(const float4*)(W + (v + 1) * 512 + k);
        float4 w2 = *(const float4*)(W + (v + 2) * 512 + k);
        float4 w3 = *(const float4*)(W + (v + 3) * 512 + k);
        a0 += jk.x * w0.x + jk.y * w0.y + jk.z * w0.z + jk.w * w0.w;
        a1 += jk.x * w1.x + jk.y * w1.y + jk.z * w1.z + jk.w * w1.w;
        a2 += jk.x * w2.x + jk.y * w2.y + jk.z * w2.z + jk.w * w2.w;
        a3 += jk.x * w3.x + jk.y * w3.y + jk.z * w3.z + jk.w * w3.w;
    }
    size_t o = (size_t)btu * 1024 + v;
    out[o] = a0; out[o + 1] = a1; out[o + 2] = a2; out[o + 3] = a3;
}

extern "C" void kernel_launch(void* const* d_in, const int* in_sizes, int n_in,
                              void* d_out, int out_size, void* d_ws, size_t ws_size,
                              hipStream_t stream) {
    const float* enc  = (const float*)d_in[0];
    const float* pred = (const float*)d_in[1];
    const float* W    = (const float*)d_in[2];
    const float* bias = (const float*)d_in[3];
    float* out = (float*)d_out;

    // ws layout: A_bf16 [2000*512] (2,048,000 B) | W_bf16 [1024*512] (1,048,576 B) | EP fp32 [2000*1024] (8,192,000 B)
    // (EP rows 0..1599 now unused; layout kept stable.)
    const size_t NEED = 2048000u + 1048576u + 8192000u;
    if (ws_size >= NEED) {
        unsigned short* AB = (unsigned short*)d_ws;
        float* EP = (float*)((char*)d_ws + 2048000 + 1048576);
        cvt_kernel<<<1512, 256, 0, stream>>>(enc, pred, W, AB);
        // P only: rows 1600..1999 (grid.x=7 covers 448 rows, clamps/guards handle tail)
        gemm_kernel<<<dim3(7, 16), 256, 0, stream>>>(AB, AB + 1024000, EP, 1600);
        fused_kernel<<<dim3(100, 8), 256, 0, stream>>>(AB, AB + 1024000, EP, bias, out);
    } else {
        fallback_kernel<<<80000, 256, 0, stream>>>(enc, pred, W, bias, out);
    }
}